// Round 1
// baseline (498.405 us; speedup 1.0000x reference)
//
#include <hip/hip_runtime.h>
#include <math.h>

#define NFFT 1024
#define HOP 256
#define NFREQ 513
#define TFRAMES 1024
#define NT_TILE 16
#define HALF 8
#define ZSTR 513
#define LFULL 262912   /* NFFT + HOP*(TFRAMES-1) */
#define LOUT  262400   /* LFULL - 512 */
#define TILE_SAMPS 4864 /* NT_TILE*HOP + (NFFT-HOP) */

__device__ __forceinline__ int rev9(int k) { return (int)(__brev((unsigned)k) >> 23); }

__global__ __launch_bounds__(256) void istft_kernel(const float2* __restrict__ x,
                                                    float* __restrict__ out) {
    __shared__ float Zre[HALF * ZSTR];
    __shared__ float Zim[HALF * ZSTR];
    __shared__ float OA[TILE_SAMPS];

    const int tid  = threadIdx.x;
    const int bc   = blockIdx.y;
    const int tile = blockIdx.x;
    const int t0   = tile * NT_TILE;
    const int S0   = t0 * HOP;

    // zero the overlap-add accumulator (each thread owns sl = tid + 256*r)
    for (int r = 0; r < 19; ++r) OA[tid + 256 * r] = 0.f;

    const float twoPiOverN = 6.2831853071795864f / 1024.f;

    for (int half = 0; half < 2; ++half) {
        // ---------- phase 1: global load + pack to half-size spectrum Z ----------
        {
            const int kg = tid >> 3;   // 0..31
            const int tt = tid & 7;    // frame within half-batch
            const int tg = t0 + half * HALF + tt;
            const long baseIn = (long)bc * NFREQ * TFRAMES;  // float2 units
            for (int i = 0; i < 9; ++i) {
                int kp = kg + 32 * i;
                if (kp > 256) break;   // only kg==0 runs i==8 (kp=256)
                float2 A  = x[baseIn + (long)kp * TFRAMES + tg];
                float2 Bc = x[baseIn + (long)(512 - kp) * TFRAMES + tg];
                float ar = A.x, ai = A.y, br = Bc.x, bi = Bc.y;
                if (kp == 0) { ai = 0.f; bi = 0.f; }  // c2r drops DC/Nyquist imag
                float si, co;
                __sincosf((float)kp * twoPiOverN, &si, &co);
                float d2r = ar - br, d2i = ai + bi;        // 2*D
                float o2r = co * d2r - si * d2i;           // 2*O = e^{i theta} * 2D
                float o2i = co * d2i + si * d2r;
                float s2r = ar + br, s2i = ai - bi;        // 2*E
                int p0 = rev9(kp);
                Zre[tt * ZSTR + p0] = 0.5f * (s2r - o2i);  // Z[kp] = E + iO
                Zim[tt * ZSTR + p0] = 0.5f * (s2i + o2r);
                if (kp >= 1 && kp <= 255) {
                    int p1 = rev9(512 - kp);               // Z[512-kp] = conj(E)+i conj(O)
                    Zre[tt * ZSTR + p1] = 0.5f * (s2r + o2i);
                    Zim[tt * ZSTR + p1] = 0.5f * (o2r - s2i);
                }
            }
        }
        __syncthreads();

        // ---------- phase 2: 8x length-512 inverse FFT (radix-2 DIT, unnormalized) ----------
        {
            const int tl = tid >> 5;  // frame 0..7
            const int h  = tid & 31;
            for (int st = 0; st < 9; ++st) {
                const int d = 1 << st;
                const float angStep = 3.14159265358979f / (float)d;
                for (int r = 0; r < 8; ++r) {
                    int j  = h + 32 * r;
                    int jm = j & (d - 1);
                    int a  = ((j >> st) << (st + 1)) + jm;
                    int b  = a + d;
                    float si, co;
                    __sincosf(angStep * (float)jm, &si, &co);
                    float are = Zre[tl * ZSTR + a], aim = Zim[tl * ZSTR + a];
                    float bre = Zre[tl * ZSTR + b], bim = Zim[tl * ZSTR + b];
                    float tre = co * bre - si * bim;
                    float tim = co * bim + si * bre;
                    Zre[tl * ZSTR + a] = are + tre;
                    Zim[tl * ZSTR + a] = aim + tim;
                    Zre[tl * ZSTR + b] = are - tre;
                    Zim[tl * ZSTR + b] = aim - tim;
                }
                __syncthreads();
            }
        }

        // ---------- phase 3: window + overlap-add into LDS accumulator ----------
        {
            const int h8 = half * HALF;
            for (int r = 0; r < 19; ++r) {       // r == floor(sl/256), wave-uniform
                int sl  = tid + 256 * r;
                int tlo = max(r - 3, h8);
                int thi = min(r, h8 + 7);
                if (tlo <= thi) {
                    float acc = 0.f;
                    for (int tl = tlo; tl <= thi; ++tl) {
                        int n   = sl - tl * HOP;          // 0..1023
                        int mm  = n >> 1;
                        int tlh = tl - h8;
                        float v = (n & 1) ? Zim[tlh * ZSTR + mm] : Zre[tlh * ZSTR + mm];
                        // win = sqrt(1024)*hann(n) / 2 / 512 = (1 - cos(2 pi n/1024)) / 64
                        float w = (1.f - __cosf((float)n * twoPiOverN)) * (1.f / 64.f);
                        acc += v * w;
                    }
                    OA[sl] += acc;
                }
            }
        }
        __syncthreads();  // protect Z before next half overwrites it
    }

    // ---------- write out: interior plain store, boundary atomicAdd ----------
    for (int r = 0; r < 19; ++r) {
        int sl = tid + 256 * r;
        int s  = S0 + sl;
        if (s < 512) continue;   // trimmed head
        float v = OA[sl];
        int o = bc * LOUT + (s - 512);
        if (sl >= 768 && sl < 4096) out[o] = v;
        else atomicAdd(&out[o], v);
    }
}

extern "C" void kernel_launch(void* const* d_in, const int* in_sizes, int n_in,
                              void* d_out, int out_size, void* d_ws, size_t ws_size,
                              hipStream_t stream) {
    const float2* x = (const float2*)d_in[0];
    float* out = (float*)d_out;
    (void)in_sizes; (void)n_in; (void)d_ws; (void)ws_size;

    hipMemsetAsync(d_out, 0, (size_t)out_size * sizeof(float), stream);

    dim3 grid(TFRAMES / NT_TILE, 64);  // 64 tiles per bc-row, 64 bc rows
    dim3 block(256);
    istft_kernel<<<grid, block, 0, stream>>>(x, out);
}